// Round 2
// baseline (2187.220 us; speedup 1.0000x reference)
//
#include <hip/hip_runtime.h>

// Problem constants (match reference)
#define N_EMBD 1024
#define N_HEAD 16
#define HD 64            // head dim
#define BSZ 4
#define TSEQ 2048
#define MROWS (BSZ * TSEQ)   // 8192

using bf16x8 = __attribute__((ext_vector_type(8))) short;
using f32x4  = __attribute__((ext_vector_type(4))) float;

// Raw-bit bf16 helpers (RN-even; inputs are finite, no NaN path needed).
__device__ __forceinline__ ushort f2bf(float f) {
    uint u = __float_as_uint(f);
    u += 0x7FFFu + ((u >> 16) & 1u);
    return (ushort)(u >> 16);
}
__device__ __forceinline__ float bf2f(ushort h) {
    return __uint_as_float(((uint)h) << 16);
}

// ---------------------------------------------------------------------------
// split_bf16: A (f32) -> H = bf16(A), L = bf16(A - H).  4 elems/thread.
// ---------------------------------------------------------------------------
__global__ __launch_bounds__(256) void split_bf16(const float* __restrict__ A,
                                                  ushort* __restrict__ H,
                                                  ushort* __restrict__ L)
{
    const size_t i = ((size_t)blockIdx.x * 256 + threadIdx.x) * 4;
    const float4 v = *(const float4*)&A[i];
    ushort4 h, l;
    h.x = f2bf(v.x); l.x = f2bf(v.x - bf2f(h.x));
    h.y = f2bf(v.y); l.y = f2bf(v.y - bf2f(h.y));
    h.z = f2bf(v.z); l.z = f2bf(v.z - bf2f(h.z));
    h.w = f2bf(v.w); l.w = f2bf(v.w - bf2f(h.w));
    *(ushort4*)&H[i] = h;
    *(ushort4*)&L[i] = l;
}

// ---------------------------------------------------------------------------
// transpose_split: W [K,N] f32 -> Th, Tl [N,K] bf16 (hi/lo split).
// 32x32 tile via LDS so both global read and write are coalesced.
// ---------------------------------------------------------------------------
__global__ __launch_bounds__(256) void transpose_split(
    const float* __restrict__ W, ushort* __restrict__ Th, ushort* __restrict__ Tl,
    int K, int N)
{
    __shared__ float t[32][33];
    const int k0 = blockIdx.y * 32;
    const int n0 = blockIdx.x * 32;
    const int c = threadIdx.x & 31;
    const int r = threadIdx.x >> 5;   // 0..7
    #pragma unroll
    for (int i = 0; i < 4; ++i)
        t[r + i * 8][c] = W[(size_t)(k0 + r + i * 8) * N + n0 + c];
    __syncthreads();
    #pragma unroll
    for (int i = 0; i < 4; ++i) {
        const float v = t[c][r + i * 8];           // = W[k0+c][n0+r+i*8]
        const ushort hb = f2bf(v);
        const ushort lb = f2bf(v - bf2f(hb));
        const size_t o = (size_t)(n0 + r + i * 8) * K + k0 + c;
        Th[o] = hb;
        Tl[o] = lb;
    }
}

// ---------------------------------------------------------------------------
// Split-bf16 MFMA GEMM: C[M,N] = (Ah+Al)[M,K] @ (Bh+Bl)^T[N,K] + bias[N]
// (keeps hi*hi + hi*lo + lo*hi; drops lo*lo -> ~1e-5 rel err vs fp32)
// 128x128 tile, BK=32, 256 threads = 4 waves, 64x64 per wave (4x4 frags of
// 16x16). mfma_f32_16x16x32_bf16. LDS rows padded to 40 bf16 (80B) so the
// stride-80B fragment reads are ~2-way (free) instead of 8-way conflicted.
// Fragment layout (gfx950): A row = lane&15, k = (lane>>4)*8 + elem;
//                           B col = lane&15, k same;
//                           D col = lane&15, row = (lane>>4)*4 + reg  [m89].
// ---------------------------------------------------------------------------
#define LDP 40

__global__ __launch_bounds__(256) void gemm_mfma_split(
    const ushort* __restrict__ Ah, const ushort* __restrict__ Al,
    const ushort* __restrict__ Bh, const ushort* __restrict__ Bl,
    const float* __restrict__ bias, float* __restrict__ C,
    int M, int N, int K)
{
    __shared__ short lds[4][128][LDP];   // 0:Ah 1:Al 2:Bh 3:Bl  (40 KiB)

    const int tid  = threadIdx.x;
    const int wave = tid >> 6;
    const int lane = tid & 63;
    const int wr   = wave >> 1;          // wave row 0..1 (64-row halves)
    const int wc   = wave & 1;           // wave col 0..1
    const int row0 = blockIdx.y * 128;
    const int col0 = blockIdx.x * 128;

    // staging: each thread moves one 16B chunk (8 bf16) per tile per half
    const int srow = tid >> 2;           // 0..63
    const int soff = (tid & 3) * 8;      // k element offset 0/8/16/24

    const int fr = lane & 15;
    const int fq = lane >> 4;
    const int ko = fq * 8;

    f32x4 acc[4][4] = {};

    for (int k0 = 0; k0 < K; k0 += 32) {
        // issue global loads early (regs only, overlaps prior MFMAs)
        float4 pa[2][2], pb[2][2];
        #pragma unroll
        for (int it = 0; it < 2; ++it) {
            const int r = srow + it * 64;
            const size_t ga = (size_t)(row0 + r) * K + k0 + soff;
            const size_t gb = (size_t)(col0 + r) * K + k0 + soff;
            pa[it][0] = *(const float4*)&Ah[ga];
            pa[it][1] = *(const float4*)&Al[ga];
            pb[it][0] = *(const float4*)&Bh[gb];
            pb[it][1] = *(const float4*)&Bl[gb];
        }
        __syncthreads();   // prior iteration's fragment reads done
        #pragma unroll
        for (int it = 0; it < 2; ++it) {
            const int r = srow + it * 64;
            *(float4*)&lds[0][r][soff] = pa[it][0];
            *(float4*)&lds[1][r][soff] = pa[it][1];
            *(float4*)&lds[2][r][soff] = pb[it][0];
            *(float4*)&lds[3][r][soff] = pb[it][1];
        }
        __syncthreads();

        bf16x8 a_h[4], a_l[4], b_h[4], b_l[4];
        #pragma unroll
        for (int m = 0; m < 4; ++m) {
            a_h[m] = *(const bf16x8*)&lds[0][wr * 64 + m * 16 + fr][ko];
            a_l[m] = *(const bf16x8*)&lds[1][wr * 64 + m * 16 + fr][ko];
        }
        #pragma unroll
        for (int n = 0; n < 4; ++n) {
            b_h[n] = *(const bf16x8*)&lds[2][wc * 64 + n * 16 + fr][ko];
            b_l[n] = *(const bf16x8*)&lds[3][wc * 64 + n * 16 + fr][ko];
        }

        #pragma unroll
        for (int m = 0; m < 4; ++m)
            #pragma unroll
            for (int n = 0; n < 4; ++n) {
                acc[m][n] = __builtin_amdgcn_mfma_f32_16x16x32_bf16(a_h[m], b_h[n], acc[m][n], 0, 0, 0);
                acc[m][n] = __builtin_amdgcn_mfma_f32_16x16x32_bf16(a_l[m], b_h[n], acc[m][n], 0, 0, 0);
                acc[m][n] = __builtin_amdgcn_mfma_f32_16x16x32_bf16(a_h[m], b_l[n], acc[m][n], 0, 0, 0);
            }
    }

    // epilogue: bias + fp32 store.  D col = lane&15, row = (lane>>4)*4 + j.
    #pragma unroll
    for (int m = 0; m < 4; ++m)
        #pragma unroll
        for (int j = 0; j < 4; ++j) {
            const size_t rr = (size_t)(row0 + wr * 64 + m * 16 + fq * 4 + j);
            #pragma unroll
            for (int n = 0; n < 4; ++n) {
                const int cc = col0 + wc * 64 + n * 16 + fr;
                C[rr * N + cc] = acc[m][n][j] + bias[cc];
            }
        }
}

// ---------------------------------------------------------------------------
// Flash attention (causal), fp32 compute; output written PRE-SPLIT to bf16
// hi/lo so it feeds the proj MFMA GEMM directly.
// qkv layout: [B*T, 3*C]; q at +h*64, k at +1024+h*64, v at +2048+h*64.
// One thread owns one q row; K/V tiles (64 rows, padded to 68 f32) in LDS.
// ---------------------------------------------------------------------------
#define QBLK 256
#define KBLK 64

__global__ __launch_bounds__(256) void flash_attn(
    const float* __restrict__ qkv,
    ushort* __restrict__ Oh, ushort* __restrict__ Ol)
{
    __shared__ float Ks[KBLK][68];
    __shared__ float Vs[KBLK][68];

    const int t = threadIdx.x;
    const int q0 = blockIdx.x * QBLK;
    const int h = blockIdx.y;
    const int b = blockIdx.z;
    const int qg = q0 + t;

    const float* qrow = qkv + ((size_t)(b * TSEQ + qg)) * (3 * N_EMBD) + h * HD;
    float q[HD];
    #pragma unroll
    for (int d4 = 0; d4 < HD; d4 += 4)
        *(float4*)&q[d4] = *(const float4*)&qrow[d4];

    float acc[HD] = {};
    float m = -1e30f, l = 0.f;

    const int lr = t >> 2;
    const int lc = (t & 3) * 16;

    const int nt = (q0 + QBLK) / KBLK;

    for (int kt = 0; kt < nt; ++kt) {
        __syncthreads();
        const float* kbase = qkv + ((size_t)(b * TSEQ + kt * KBLK + lr)) * (3 * N_EMBD)
                             + N_EMBD + h * HD + lc;
        const float* vbase = kbase + N_EMBD;
        #pragma unroll
        for (int w = 0; w < 4; ++w) {
            *(float4*)&Ks[lr][lc + w * 4] = *(const float4*)&kbase[w * 4];
            *(float4*)&Vs[lr][lc + w * 4] = *(const float4*)&vbase[w * 4];
        }
        __syncthreads();

        const int kg0 = kt * KBLK;
        #pragma unroll 1
        for (int c = 0; c < KBLK / 16; ++c) {
            if (kg0 + c * 16 > qg) continue;     // fully-masked chunk

            float s[16];
            float tmax = -1e30f;
            #pragma unroll
            for (int jj = 0; jj < 16; ++jj) {
                const int j = c * 16 + jj;
                float dot = 0.f;
                #pragma unroll
                for (int d4 = 0; d4 < HD; d4 += 4) {
                    const float4 kv = *(const float4*)&Ks[j][d4];
                    dot += q[d4 + 0] * kv.x + q[d4 + 1] * kv.y
                         + q[d4 + 2] * kv.z + q[d4 + 3] * kv.w;
                }
                s[jj] = (kg0 + j <= qg) ? dot * 0.125f : -1e30f;
                tmax = fmaxf(tmax, s[jj]);
            }

            const float mn = fmaxf(m, tmax);
            const float sf = __expf(m - mn);     // 0 when m was -inf-like
            m = mn;
            l *= sf;
            #pragma unroll
            for (int d = 0; d < HD; ++d) acc[d] *= sf;

            #pragma unroll
            for (int jj = 0; jj < 16; ++jj) {
                const float p = __expf(s[jj] - mn);   // masked -> 0
                l += p;
                const int j = c * 16 + jj;
                #pragma unroll
                for (int d4 = 0; d4 < HD; d4 += 4) {
                    const float4 vv = *(const float4*)&Vs[j][d4];
                    acc[d4 + 0] += p * vv.x;
                    acc[d4 + 1] += p * vv.y;
                    acc[d4 + 2] += p * vv.z;
                    acc[d4 + 3] += p * vv.w;
                }
            }
        }
    }

    const float inv = 1.f / l;
    const size_t base = ((size_t)(b * TSEQ + qg)) * N_EMBD + h * HD;
    #pragma unroll
    for (int d8 = 0; d8 < HD; d8 += 8) {
        ushort hh[8] __attribute__((aligned(16)));
        ushort ll[8] __attribute__((aligned(16)));
        #pragma unroll
        for (int u = 0; u < 8; ++u) {
            const float y = acc[d8 + u] * inv;
            hh[u] = f2bf(y);
            ll[u] = f2bf(y - bf2f(hh[u]));
        }
        *(float4*)&Oh[base + d8] = *(const float4*)hh;
        *(float4*)&Ol[base + d8] = *(const float4*)ll;
    }
}

// ---------------------------------------------------------------------------
// Orchestration. Workspace layout (176 MB total, all written before read):
//   qkv  f32 [8192,3072]                96 MB
//   xh/xl bf16 [8192,1024]              16+16 MB
//   wah/wal bf16 [3072,1024] (W_attn^T)  6+6 MB
//   wph/wpl bf16 [1024,1024] (W_proj^T)  2+2 MB
//   ath/atl bf16 [8192,1024]            16+16 MB
// ---------------------------------------------------------------------------
extern "C" void kernel_launch(void* const* d_in, const int* in_sizes, int n_in,
                              void* d_out, int out_size, void* d_ws, size_t ws_size,
                              hipStream_t stream) {
    const float* x      = (const float*)d_in[0];
    const float* W_attn = (const float*)d_in[1];
    const float* b_attn = (const float*)d_in[2];
    const float* W_proj = (const float*)d_in[3];
    const float* b_proj = (const float*)d_in[4];
    float* out = (float*)d_out;

    char* ws = (char*)d_ws;
    float*  qkv = (float*)ws;  ws += (size_t)MROWS * 3 * N_EMBD * sizeof(float);
    ushort* xh  = (ushort*)ws; ws += (size_t)MROWS * N_EMBD * 2;
    ushort* xl  = (ushort*)ws; ws += (size_t)MROWS * N_EMBD * 2;
    ushort* wah = (ushort*)ws; ws += (size_t)3 * N_EMBD * N_EMBD * 2;
    ushort* wal = (ushort*)ws; ws += (size_t)3 * N_EMBD * N_EMBD * 2;
    ushort* wph = (ushort*)ws; ws += (size_t)N_EMBD * N_EMBD * 2;
    ushort* wpl = (ushort*)ws; ws += (size_t)N_EMBD * N_EMBD * 2;
    ushort* ath = (ushort*)ws; ws += (size_t)MROWS * N_EMBD * 2;
    ushort* atl = (ushort*)ws;

    dim3 blk(256);

    // input splits / weight transpose+splits
    split_bf16<<<dim3(MROWS * N_EMBD / 1024), blk, 0, stream>>>(x, xh, xl);
    transpose_split<<<dim3(3 * N_EMBD / 32, N_EMBD / 32), blk, 0, stream>>>(
        W_attn, wah, wal, N_EMBD, 3 * N_EMBD);
    transpose_split<<<dim3(N_EMBD / 32, N_EMBD / 32), blk, 0, stream>>>(
        W_proj, wph, wpl, N_EMBD, N_EMBD);

    // qkv = x @ W_attn + b_attn   (M=8192, N=3072, K=1024)
    gemm_mfma_split<<<dim3(3 * N_EMBD / 128, MROWS / 128), blk, 0, stream>>>(
        xh, xl, wah, wal, b_attn, qkv, MROWS, 3 * N_EMBD, N_EMBD);

    // attention (fp32 compute, bf16-split output)
    flash_attn<<<dim3(TSEQ / QBLK, N_HEAD, BSZ), blk, 0, stream>>>(qkv, ath, atl);

    // out = attout @ W_proj + b_proj   (M=8192, N=1024, K=1024)
    gemm_mfma_split<<<dim3(N_EMBD / 128, MROWS / 128), blk, 0, stream>>>(
        ath, atl, wph, wpl, b_proj, out, MROWS, N_EMBD, N_EMBD);
}

// Round 3
// 993.882 us; speedup vs baseline: 2.2007x; 2.2007x over previous
//
#include <hip/hip_runtime.h>

// Problem constants (match reference)
#define N_EMBD 1024
#define N_HEAD 16
#define HD 64            // head dim
#define BSZ 4
#define TSEQ 2048
#define MROWS (BSZ * TSEQ)   // 8192

using bf16x8 = __attribute__((ext_vector_type(8))) short;
using f32x4  = __attribute__((ext_vector_type(4))) float;

// Raw-bit bf16 helpers (RN-even).
__device__ __forceinline__ ushort f2bf(float f) {
    uint u = __float_as_uint(f);
    u += 0x7FFFu + ((u >> 16) & 1u);
    return (ushort)(u >> 16);
}
__device__ __forceinline__ float bf2f(ushort h) {
    return __uint_as_float(((uint)h) << 16);
}

// ---------------------------------------------------------------------------
// split_bf16: A (f32) -> H = bf16(A), L = bf16(A - H).  4 elems/thread.
// ---------------------------------------------------------------------------
__global__ __launch_bounds__(256) void split_bf16(const float* __restrict__ A,
                                                  ushort* __restrict__ H,
                                                  ushort* __restrict__ L)
{
    const size_t i = ((size_t)blockIdx.x * 256 + threadIdx.x) * 4;
    const float4 v = *(const float4*)&A[i];
    ushort4 h, l;
    h.x = f2bf(v.x); l.x = f2bf(v.x - bf2f(h.x));
    h.y = f2bf(v.y); l.y = f2bf(v.y - bf2f(h.y));
    h.z = f2bf(v.z); l.z = f2bf(v.z - bf2f(h.z));
    h.w = f2bf(v.w); l.w = f2bf(v.w - bf2f(h.w));
    *(ushort4*)&H[i] = h;
    *(ushort4*)&L[i] = l;
}

// ---------------------------------------------------------------------------
// transpose_split: W [K,N] f32 -> Th, Tl [N,K] bf16 (hi/lo split).
// ---------------------------------------------------------------------------
__global__ __launch_bounds__(256) void transpose_split(
    const float* __restrict__ W, ushort* __restrict__ Th, ushort* __restrict__ Tl,
    int K, int N)
{
    __shared__ float t[32][33];
    const int k0 = blockIdx.y * 32;
    const int n0 = blockIdx.x * 32;
    const int c = threadIdx.x & 31;
    const int r = threadIdx.x >> 5;   // 0..7
    #pragma unroll
    for (int i = 0; i < 4; ++i)
        t[r + i * 8][c] = W[(size_t)(k0 + r + i * 8) * N + n0 + c];
    __syncthreads();
    #pragma unroll
    for (int i = 0; i < 4; ++i) {
        const float v = t[c][r + i * 8];           // = W[k0+c][n0+r+i*8]
        const ushort hb = f2bf(v);
        const ushort lb = f2bf(v - bf2f(hb));
        const size_t o = (size_t)(n0 + r + i * 8) * K + k0 + c;
        Th[o] = hb;
        Tl[o] = lb;
    }
}

// ---------------------------------------------------------------------------
// transpose_v: qkvh v-part [B*T, 2048+h*64+d] bf16 -> vth [b,h,d,t] bf16.
// 64x64 tiles via LDS.
// ---------------------------------------------------------------------------
__global__ __launch_bounds__(256) void transpose_v(
    const ushort* __restrict__ qkvh, ushort* __restrict__ vth)
{
    __shared__ ushort tr[64][65];
    const int t0 = blockIdx.x * 64;
    const int h  = blockIdx.y;
    const int b  = blockIdx.z;
    const int r  = threadIdx.x >> 2;         // 0..63
    const int c4 = (threadIdx.x & 3) * 16;   // 0,16,32,48

    const size_t inb = ((size_t)(b * TSEQ + t0 + r)) * (3 * N_EMBD) + 2 * N_EMBD + h * HD + c4;
    *(float4*)&tr[r][c4]     = *(const float4*)&qkvh[inb];
    *(float4*)&tr[r][c4 + 8] = *(const float4*)&qkvh[inb + 8];
    __syncthreads();

    ushort v[16] __attribute__((aligned(16)));
    #pragma unroll
    for (int u = 0; u < 16; ++u) v[u] = tr[c4 + u][r];   // = V[t0+c4+u][d=r]
    const size_t ob = (((size_t)(b * N_HEAD + h)) * HD + r) * TSEQ + t0 + c4;
    *(float4*)&vth[ob]     = ((const float4*)v)[0];
    *(float4*)&vth[ob + 8] = ((const float4*)v)[1];
}

// ---------------------------------------------------------------------------
// Split-bf16 MFMA GEMM.  C[M,N] = A[M,K] @ B^T[N,K] + bias.
// ASPLIT: A has hi+lo planes (3-term: AhBh+AlBh+AhBl); else 2-term (AhBh+AhBl).
// OUTBF16: write hi/lo bf16 planes; else f32.
// 128x128 tile, BK=32, 4 waves, 64x64/wave, 4x4 16x16x32 frags.
// LDS rows padded to 34 shorts (17 words, odd) -> 2-way (free) frag reads.
// ---------------------------------------------------------------------------
#define LDP 34

template<bool ASPLIT, bool OUTBF16>
__global__ __launch_bounds__(256) void gemm_mfma(
    const ushort* __restrict__ Ah, const ushort* __restrict__ Al,
    const ushort* __restrict__ Bh, const ushort* __restrict__ Bl,
    const float* __restrict__ bias,
    float* __restrict__ Cf, ushort* __restrict__ Ch, ushort* __restrict__ Cl,
    int M, int N, int K)
{
    __shared__ short lds[4][128][LDP];   // 0:Ah 1:Al 2:Bh 3:Bl

    const int tid  = threadIdx.x;
    const int wave = tid >> 6;
    const int lane = tid & 63;
    const int wr   = wave >> 1;
    const int wc   = wave & 1;
    const int row0 = blockIdx.y * 128;
    const int col0 = blockIdx.x * 128;

    const int srow = tid >> 2;           // 0..63
    const int soff = (tid & 3) * 8;      // 0,8,16,24

    const int fr = lane & 15;
    const int fq = lane >> 4;
    const int ko = fq * 8;

    f32x4 acc[4][4] = {};

    for (int k0 = 0; k0 < K; k0 += 32) {
        float4 pa[2][2], pb[2][2];
        #pragma unroll
        for (int it = 0; it < 2; ++it) {
            const int r = srow + it * 64;
            const size_t ga = (size_t)(row0 + r) * K + k0 + soff;
            const size_t gb = (size_t)(col0 + r) * K + k0 + soff;
            pa[it][0] = *(const float4*)&Ah[ga];
            if (ASPLIT) pa[it][1] = *(const float4*)&Al[ga];
            pb[it][0] = *(const float4*)&Bh[gb];
            pb[it][1] = *(const float4*)&Bl[gb];
        }
        __syncthreads();
        #pragma unroll
        for (int it = 0; it < 2; ++it) {
            const int r = srow + it * 64;
            *(float4*)&lds[0][r][soff] = pa[it][0];
            if (ASPLIT) *(float4*)&lds[1][r][soff] = pa[it][1];
            *(float4*)&lds[2][r][soff] = pb[it][0];
            *(float4*)&lds[3][r][soff] = pb[it][1];
        }
        __syncthreads();

        bf16x8 a_h[4], a_l[4], b_h[4], b_l[4];
        #pragma unroll
        for (int m = 0; m < 4; ++m) {
            a_h[m] = *(const bf16x8*)&lds[0][wr * 64 + m * 16 + fr][ko];
            if (ASPLIT) a_l[m] = *(const bf16x8*)&lds[1][wr * 64 + m * 16 + fr][ko];
        }
        #pragma unroll
        for (int n = 0; n < 4; ++n) {
            b_h[n] = *(const bf16x8*)&lds[2][wc * 64 + n * 16 + fr][ko];
            b_l[n] = *(const bf16x8*)&lds[3][wc * 64 + n * 16 + fr][ko];
        }

        #pragma unroll
        for (int m = 0; m < 4; ++m)
            #pragma unroll
            for (int n = 0; n < 4; ++n) {
                acc[m][n] = __builtin_amdgcn_mfma_f32_16x16x32_bf16(a_h[m], b_h[n], acc[m][n], 0, 0, 0);
                if (ASPLIT)
                    acc[m][n] = __builtin_amdgcn_mfma_f32_16x16x32_bf16(a_l[m], b_h[n], acc[m][n], 0, 0, 0);
                acc[m][n] = __builtin_amdgcn_mfma_f32_16x16x32_bf16(a_h[m], b_l[n], acc[m][n], 0, 0, 0);
            }
    }

    // epilogue: D col = lane&15, row = (lane>>4)*4 + j  [HW-verified r1]
    #pragma unroll
    for (int m = 0; m < 4; ++m)
        #pragma unroll
        for (int j = 0; j < 4; ++j) {
            const size_t rr = (size_t)(row0 + wr * 64 + m * 16 + fq * 4 + j);
            #pragma unroll
            for (int n = 0; n < 4; ++n) {
                const int cc = col0 + wc * 64 + n * 16 + fr;
                const float o = acc[m][n][j] + bias[cc];
                if (OUTBF16) {
                    const ushort hb = f2bf(o);
                    Ch[rr * N + cc] = hb;
                    Cl[rr * N + cc] = f2bf(o - bf2f(hb));
                } else {
                    Cf[rr * N + cc] = o;
                }
            }
        }
}

// ---------------------------------------------------------------------------
// MFMA flash attention (causal).
// 8 waves x 16 q-rows = QBLK 128; KBLK 64.
// S^T = mfma(A=K, B=Q): per-q state at col=lane&15 -> shfl_xor(16/32) reduce,
// per-lane-uniform rescale of O^T.  P re-laid out via wave-private LDS.
// O^T = mfma(A=V^T, B=P).  V^T from vth [b,h,d,t].
// Split: QK 3-term (Kh/Kl x Qh/Ql), PV 2-term (Ph+Pl, V hi).
// Output: bf16 hi plane only (error contracts through W_proj).
// ---------------------------------------------------------------------------
__global__ __launch_bounds__(512, 4) void flash_attn_mfma(
    const ushort* __restrict__ qkvh, const ushort* __restrict__ qkvl,
    const ushort* __restrict__ vth, ushort* __restrict__ ath)
{
    __shared__ short Kh[64][66];          // 8448 B
    __shared__ short Kl[64][66];          // 8448 B
    __shared__ short Vs[64][66];          // 8448 B  [d][k_local]
    __shared__ short Pw[8][2][16][68];    // 34816 B [wave][hi/lo][q][k]

    const int tid  = threadIdx.x;
    const int wave = tid >> 6;
    const int lane = tid & 63;
    const int fr = lane & 15;
    const int g  = lane >> 4;
    const int q0 = blockIdx.x * 128;
    const int h  = blockIdx.y;
    const int b  = blockIdx.z;
    const int qw = q0 + wave * 16;       // wave's first q row
    const int qg = qw + fr;              // this lane's q (B-col)

    // Q fragments: B[c][q] needs Q[q][c0+8g+e]
    const size_t qrow = ((size_t)(b * TSEQ + qg)) * (3 * N_EMBD) + h * HD + 8 * g;
    const bf16x8 qh0 = *(const bf16x8*)&qkvh[qrow];
    const bf16x8 qh1 = *(const bf16x8*)&qkvh[qrow + 32];
    const bf16x8 ql0 = *(const bf16x8*)&qkvl[qrow];
    const bf16x8 ql1 = *(const bf16x8*)&qkvl[qrow + 32];

    f32x4 O[4] = {};
    float mrun = -1e30f, lrun = 0.f;

    // staging: thread moves 8 bf16 per plane
    const int sr = tid >> 3;             // 0..63
    const int sc = (tid & 7) * 8;        // 0..56
    const ushort* kgh = qkvh + ((size_t)(b * TSEQ + sr)) * (3 * N_EMBD) + N_EMBD + h * HD + sc;
    const ushort* kgl = qkvl + ((size_t)(b * TSEQ + sr)) * (3 * N_EMBD) + N_EMBD + h * HD + sc;
    const ushort* vg  = vth + (((size_t)(b * N_HEAD + h)) * HD + sr) * TSEQ + sc;

    const int nt = q0 / 64 + 2;
    for (int kt = 0; kt < nt; ++kt) {
        const float4 rkh = *(const float4*)(kgh + (size_t)kt * 64 * 3 * N_EMBD);
        const float4 rkl = *(const float4*)(kgl + (size_t)kt * 64 * 3 * N_EMBD);
        const float4 rv  = *(const float4*)(vg + kt * 64);
        __syncthreads();                 // prior tile reads done
        *(float4*)&Kh[sr][sc] = rkh;
        *(float4*)&Kl[sr][sc] = rkl;
        *(float4*)&Vs[sr][sc] = rv;
        __syncthreads();

        if (kt * 64 > qw + 15) continue;     // fully masked for this wave

        // ---- QK^T: S^T[k][q], frag kf covers k_local = kf*16 + 4g + j ----
        f32x4 s[4] = {};
        #pragma unroll
        for (int kf = 0; kf < 4; ++kf) {
            const bf16x8 kh0 = *(const bf16x8*)&Kh[kf * 16 + fr][8 * g];
            const bf16x8 kl0 = *(const bf16x8*)&Kl[kf * 16 + fr][8 * g];
            const bf16x8 kh1 = *(const bf16x8*)&Kh[kf * 16 + fr][32 + 8 * g];
            const bf16x8 kl1 = *(const bf16x8*)&Kl[kf * 16 + fr][32 + 8 * g];
            s[kf] = __builtin_amdgcn_mfma_f32_16x16x32_bf16(kh0, qh0, s[kf], 0, 0, 0);
            s[kf] = __builtin_amdgcn_mfma_f32_16x16x32_bf16(kl0, qh0, s[kf], 0, 0, 0);
            s[kf] = __builtin_amdgcn_mfma_f32_16x16x32_bf16(kh0, ql0, s[kf], 0, 0, 0);
            s[kf] = __builtin_amdgcn_mfma_f32_16x16x32_bf16(kh1, qh1, s[kf], 0, 0, 0);
            s[kf] = __builtin_amdgcn_mfma_f32_16x16x32_bf16(kl1, qh1, s[kf], 0, 0, 0);
            s[kf] = __builtin_amdgcn_mfma_f32_16x16x32_bf16(kh1, ql1, s[kf], 0, 0, 0);
        }

        // ---- scale + causal mask + per-q max (4-lane-group reduce) ----
        const bool dm = (kt * 64 + 63 > qw);
        float tmax = -1e30f;
        #pragma unroll
        for (int kf = 0; kf < 4; ++kf)
            #pragma unroll
            for (int j = 0; j < 4; ++j) {
                float v = s[kf][j] * 0.125f;
                if (dm && (kt * 64 + kf * 16 + 4 * g + j > qg)) v = -1e30f;
                s[kf][j] = v;
                tmax = fmaxf(tmax, v);
            }
        tmax = fmaxf(tmax, __shfl_xor(tmax, 16));
        tmax = fmaxf(tmax, __shfl_xor(tmax, 32));
        const float mn = fmaxf(mrun, tmax);
        const float sf = __expf(mrun - mn);
        mrun = mn;
        lrun *= sf;
        #pragma unroll
        for (int df = 0; df < 4; ++df)
            #pragma unroll
            for (int j = 0; j < 4; ++j) O[df][j] *= sf;

        // ---- P = exp(S-m), bf16 hi/lo, l from ROUNDED p (consistent norm) ----
        #pragma unroll
        for (int kf = 0; kf < 4; ++kf) {
            uint hw0, hw1, lw0, lw1;
            {
                const float p0 = __expf(s[kf][0] - mn);
                const float p1 = __expf(s[kf][1] - mn);
                const float p2 = __expf(s[kf][2] - mn);
                const float p3 = __expf(s[kf][3] - mn);
                const ushort h0 = f2bf(p0), h1 = f2bf(p1), h2 = f2bf(p2), h3 = f2bf(p3);
                const ushort l0 = f2bf(p0 - bf2f(h0)), l1 = f2bf(p1 - bf2f(h1));
                const ushort l2 = f2bf(p2 - bf2f(h2)), l3 = f2bf(p3 - bf2f(h3));
                lrun += (bf2f(h0) + bf2f(l0)) + (bf2f(h1) + bf2f(l1))
                      + (bf2f(h2) + bf2f(l2)) + (bf2f(h3) + bf2f(l3));
                hw0 = (uint)h0 | ((uint)h1 << 16);
                hw1 = (uint)h2 | ((uint)h3 << 16);
                lw0 = (uint)l0 | ((uint)l1 << 16);
                lw1 = (uint)l2 | ((uint)l3 << 16);
            }
            const int kb = kf * 16 + 4 * g;
            *(uint*)&Pw[wave][0][fr][kb]     = hw0;
            *(uint*)&Pw[wave][0][fr][kb + 2] = hw1;
            *(uint*)&Pw[wave][1][fr][kb]     = lw0;
            *(uint*)&Pw[wave][1][fr][kb + 2] = lw1;
        }

        // ---- PV: O^T[d][q] += V^T x P  (2-term: Ph + Pl) ----
        #pragma unroll
        for (int c = 0; c < 2; ++c) {
            const bf16x8 pbh = *(const bf16x8*)&Pw[wave][0][fr][c * 32 + 8 * g];
            const bf16x8 pbl = *(const bf16x8*)&Pw[wave][1][fr][c * 32 + 8 * g];
            #pragma unroll
            for (int df = 0; df < 4; ++df) {
                const bf16x8 va = *(const bf16x8*)&Vs[df * 16 + fr][c * 32 + 8 * g];
                O[df] = __builtin_amdgcn_mfma_f32_16x16x32_bf16(va, pbh, O[df], 0, 0, 0);
                O[df] = __builtin_amdgcn_mfma_f32_16x16x32_bf16(va, pbl, O[df], 0, 0, 0);
            }
        }
    }

    // ---- finalize: l reduce over g, normalize, transpose O via wave LDS ----
    lrun += __shfl_xor(lrun, 16);
    lrun += __shfl_xor(lrun, 32);
    const float inv = 1.f / lrun;

    float* Ol = (float*)&Pw[wave][0][0][0];   // [16][68] f32 = 4352 B (exact fit)
    #pragma unroll
    for (int df = 0; df < 4; ++df)
        #pragma unroll
        for (int j = 0; j < 4; ++j)
            Ol[fr * 68 + df * 16 + 4 * g + j] = O[df][j] * inv;

    const int q2 = lane >> 2;
    const int dl = (lane & 3) * 4;
    const size_t orow = ((size_t)(b * TSEQ + q0 + wave * 16 + q2)) * N_EMBD + h * HD;
    #pragma unroll
    for (int i = 0; i < 4; ++i) {
        const float4 y = *(const float4*)&Ol[q2 * 68 + dl + 16 * i];
        ushort4 o4;
        o4.x = f2bf(y.x); o4.y = f2bf(y.y); o4.z = f2bf(y.z); o4.w = f2bf(y.w);
        *(ushort4*)&ath[orow + dl + 16 * i] = o4;
    }
}

// ---------------------------------------------------------------------------
// Orchestration.  Workspace (== round-1's proven 184,549,376 B):
//   qkvh/qkvl bf16 [8192,3072]  48+48 MB
//   xh/xl     bf16 [8192,1024]  16+16 MB
//   wah/wal   bf16 [3072,1024]   6+6 MB   (W_attn^T)
//   wph/wpl   bf16 [1024,1024]   2+2 MB   (W_proj^T)
//   vth       bf16 [64,64,2048] 16 MB     (V^T per b,h)
//   ath       bf16 [8192,1024]  16 MB
// ---------------------------------------------------------------------------
extern "C" void kernel_launch(void* const* d_in, const int* in_sizes, int n_in,
                              void* d_out, int out_size, void* d_ws, size_t ws_size,
                              hipStream_t stream) {
    const float* x      = (const float*)d_in[0];
    const float* W_attn = (const float*)d_in[1];
    const float* b_attn = (const float*)d_in[2];
    const float* W_proj = (const float*)d_in[3];
    const float* b_proj = (const float*)d_in[4];
    float* out = (float*)d_out;
    (void)in_sizes; (void)n_in; (void)out_size; (void)ws_size;

    char* ws = (char*)d_ws;
    ushort* qkvh = (ushort*)ws; ws += (size_t)MROWS * 3 * N_EMBD * 2;
    ushort* qkvl = (ushort*)ws; ws += (size_t)MROWS * 3 * N_EMBD * 2;
    ushort* xh   = (ushort*)ws; ws += (size_t)MROWS * N_EMBD * 2;
    ushort* xl   = (ushort*)ws; ws += (size_t)MROWS * N_EMBD * 2;
    ushort* wah  = (ushort*)ws; ws += (size_t)3 * N_EMBD * N_EMBD * 2;
    ushort* wal  = (ushort*)ws; ws += (size_t)3 * N_EMBD * N_EMBD * 2;
    ushort* wph  = (ushort*)ws; ws += (size_t)N_EMBD * N_EMBD * 2;
    ushort* wpl  = (ushort*)ws; ws += (size_t)N_EMBD * N_EMBD * 2;
    ushort* vth  = (ushort*)ws; ws += (size_t)MROWS * N_EMBD * 2;
    ushort* ath  = (ushort*)ws;

    dim3 blk(256);

    split_bf16<<<dim3(MROWS * N_EMBD / 1024), blk, 0, stream>>>(x, xh, xl);
    transpose_split<<<dim3(3 * N_EMBD / 32, N_EMBD / 32), blk, 0, stream>>>(
        W_attn, wah, wal, N_EMBD, 3 * N_EMBD);
    transpose_split<<<dim3(N_EMBD / 32, N_EMBD / 32), blk, 0, stream>>>(
        W_proj, wph, wpl, N_EMBD, N_EMBD);

    // qkv = x @ W_attn + b_attn  -> bf16 hi/lo
    gemm_mfma<true, true><<<dim3(3 * N_EMBD / 128, MROWS / 128), blk, 0, stream>>>(
        xh, xl, wah, wal, b_attn, nullptr, qkvh, qkvl, MROWS, 3 * N_EMBD, N_EMBD);

    // V^T
    transpose_v<<<dim3(TSEQ / 64, N_HEAD, BSZ), blk, 0, stream>>>(qkvh, vth);

    // attention
    flash_attn_mfma<<<dim3(TSEQ / 128, N_HEAD, BSZ), dim3(512), 0, stream>>>(
        qkvh, qkvl, vth, ath);

    // out = attout @ W_proj + b_proj  (A hi-only, 2-term)
    gemm_mfma<false, false><<<dim3(N_EMBD / 128, MROWS / 128), blk, 0, stream>>>(
        ath, nullptr, wph, wpl, b_proj, out, nullptr, nullptr, MROWS, N_EMBD, N_EMBD);
}